// Round 21
// baseline (283.406 us; speedup 1.0000x reference)
//
#include <hip/hip_runtime.h>
#include <hip/hip_fp8.h>
#include <math.h>

#define NR 4096
#define UD 64
#define BD 256
#define SD 256
#define RD 512
#define UBD 16384
#define DECAY 0.99f

typedef unsigned char u8;
typedef __attribute__((ext_vector_type(4))) float f32x4;
typedef __attribute__((ext_vector_type(2))) long longx2;

// output offsets (in floats), concatenated in reference return order
#define OFF_MDR   0ull
#define OFF_MSIG  2097152ull
#define OFF_MCONF 3145728ull
#define OFF_NDP   3149824ull
#define OFF_NSP   11538432ull
#define OFF_NEC   15732736ull
#define OFF_NUS   15749120ull
#define OFF_SCAL  15765504ull

static __device__ __forceinline__ u8 f2e4m3(float x) {
  __hip_fp8_e4m3 h(x);
  return (u8)h.__x;
}

static __device__ __forceinline__ void gll16(const void* g, void* l) {
  __builtin_amdgcn_global_load_lds(
      (const __attribute__((address_space(1))) unsigned int*)g,
      (__attribute__((address_space(3))) unsigned int*)l, 16, 0, 0);
}

// k-order permutation within a 64-block: b = ks8*32 + kg*8 + e -> kg*16 + ks8*8 + e
static __device__ __forceinline__ int perm64(int x) {
  return (((x >> 3) & 3) << 4) | (((x >> 5) & 1) << 3) | (x & 7);
}

// ---------------------------------------------------------------------------
// prep_all: [0,1024) qb8 convert | [1024,1088) quT | [1088,4160) PT8 transpose
// | [4160,4416) row_prep (16 rows/block, fused sum_w/cnt atomics)
__global__ __launch_bounds__(256) void prep_all_kernel(
    const float* __restrict__ q_u, const float* __restrict__ q_b,
    const float* __restrict__ dproto, const float* __restrict__ sproto,
    const float* __restrict__ usage, const float* __restrict__ ema,
    const unsigned char* __restrict__ wm,
    u8* __restrict__ qb8, float* __restrict__ quT, u8* __restrict__ PT8,
    float* __restrict__ denom, float* __restrict__ base_raw,
    float* __restrict__ wgt, int* __restrict__ cellid, float* __restrict__ mrow,
    float* __restrict__ sum_w, float* __restrict__ cnt)
{
  __shared__ __attribute__((aligned(16))) u8 sbuf[53248];
  __shared__ int s_flag;
  const int b = blockIdx.x;
  const int tid = threadIdx.x;

  if (b < 1024) {
    const int i = b * 256 + tid;
    const int idx = i * 4;
    const int row = idx >> 8;
    const int bb  = idx & 255;
    const float4 v = *(const float4*)(q_b + (size_t)idx);
    u8 tmp[4] = { f2e4m3(v.x), f2e4m3(v.y), f2e4m3(v.z), f2e4m3(v.w) };
    unsigned int wv; __builtin_memcpy(&wv, tmp, 4);
    const int nb = (bb & ~63) | perm64(bb & 63);
    *(unsigned int*)(qb8 + (size_t)row * BD + nb) = wv;
    return;
  }
  if (b < 1088) {
    float (*s)[65] = (float(*)[65])sbuf;
    const int n0 = (b - 1024) * 64;
    #pragma unroll
    for (int i = 0; i < 16; ++i) {
      const int idx = tid + i * 256;
      const int r = idx >> 6, u = idx & 63;
      s[r][u] = q_u[(size_t)(n0 + r) * UD + u];
    }
    __syncthreads();
    #pragma unroll
    for (int i = 0; i < 16; ++i) {
      const int idx = tid + i * 256;
      const int u = idx >> 6, r = idx & 63;
      quT[(size_t)u * NR + n0 + r] = s[r][u];
    }
    return;
  }
  if (b < 4160) {
    u8 (*s)[68] = (u8(*)[68])sbuf;
    const int idx = b - 1088;
    const int k0 = (idx & 255) * 64;
    const int rblk = idx >> 8;       // 0..11
    const float* src; int ld; int c0s;
    if (rblk < 8) { src = dproto; ld = RD; c0s = rblk * 64; }
    else          { src = sproto; ld = SD; c0s = (rblk - 8) * 64; }
    const int kl = tid >> 4;
    const int rl = (tid & 15) * 4;
    #pragma unroll
    for (int i = 0; i < 4; ++i) {
      const int k = kl + i * 16;
      const bool valid = usage[k0 + k] > 0.f;
      const float4 v = *(const float4*)(src + (size_t)(k0 + k) * ld + c0s + rl);
      s[k][rl + 0] = valid ? f2e4m3(v.x) : (u8)0;
      s[k][rl + 1] = valid ? f2e4m3(v.y) : (u8)0;
      s[k][rl + 2] = valid ? f2e4m3(v.z) : (u8)0;
      s[k][rl + 3] = valid ? f2e4m3(v.w) : (u8)0;
    }
    __syncthreads();
    const int rl2 = tid >> 4;
    const int kl2 = (tid & 15) * 4;
    #pragma unroll
    for (int i = 0; i < 4; ++i) {
      const int r = rl2 + i * 16;
      u8 tmp[4] = { s[kl2 + 0][r], s[kl2 + 1][r], s[kl2 + 2][r], s[kl2 + 3][r] };
      unsigned int wv; __builtin_memcpy(&wv, tmp, 4);
      *(unsigned int*)(PT8 + (size_t)(rblk * 64 + r) * UBD + k0 + perm64(kl2)) = wv;
    }
    return;
  }
  // ---- row_prep: 16 rows/block
  {
    float (*s_qu)[64]   = (float(*)[64])sbuf;
    float (*s_qbv)[256] = (float(*)[256])(sbuf + 4096);
    float (*s_pd)[256]  = (float(*)[256])(sbuf + 20480);
    float (*s_pc)[256]  = (float(*)[256])(sbuf + 36864);
    const int r0 = (b - 4160) * 16;
    {
      const float4 v = *(const float4*)(q_u + (size_t)r0 * UD + tid * 4);
      float* dst = &s_qu[0][0] + tid * 4;
      dst[0] = v.x; dst[1] = v.y; dst[2] = v.z; dst[3] = v.w;
    }
    {
      const float4* src = (const float4*)(q_b + (size_t)r0 * BD);
      float4* dst = (float4*)&s_qbv[0][0];
      #pragma unroll
      for (int i = 0; i < 4; ++i) dst[tid + i * 256] = src[tid + i * 256];
    }
    if (tid == 0) {
      const int*   wi = (const int*)wm;
      const float* wf = (const float*)wm;
      bool is_i32 = true, is_f32 = true;
      #pragma unroll
      for (int i = 0; i < 16; ++i) {
        int v = wi[i];
        if (v != 0 && v != 1) is_i32 = false;
        float f = wf[i];
        if (f != 0.f && f != 1.f) is_f32 = false;
      }
      s_flag = is_i32 ? 2 : (is_f32 ? 1 : 0);
    }
    __syncthreads();
    float accd[16], accc[16];
    #pragma unroll
    for (int r = 0; r < 16; ++r) { accd[r] = 0.f; accc[r] = 0.f; }
    #pragma unroll 2
    for (int u = 0; u < UD; ++u) {
      const float us = usage[u * BD + tid];
      const float em = ema[u * BD + tid];
      const float vm = (us > 0.f) ? 1.f : 0.f;
      const float ev = em * vm;
      #pragma unroll
      for (int r = 0; r < 16; ++r) {
        accd[r] += s_qu[r][u] * vm;
        accc[r] += s_qu[r][u] * ev;
      }
    }
    #pragma unroll
    for (int r = 0; r < 16; ++r) {
      s_pd[r][tid] = accd[r] * s_qbv[r][tid];
      s_pc[r][tid] = accc[r] * s_qbv[r][tid];
    }
    __syncthreads();
    const int w = tid >> 6, l = tid & 63;
    #pragma unroll
    for (int rr = 0; rr < 4; ++rr) {
      const int row = w * 4 + rr;
      float dsum = s_pd[row][l] + s_pd[row][l + 64] + s_pd[row][l + 128] + s_pd[row][l + 192];
      float csum = s_pc[row][l] + s_pc[row][l + 64] + s_pc[row][l + 128] + s_pc[row][l + 192];
      #pragma unroll
      for (int m = 1; m < 64; m <<= 1) {
        dsum += __shfl_xor(dsum, m);
        csum += __shfl_xor(csum, m);
      }
      float bv_ = s_qbv[row][l]; int bi_ = l;
      #pragma unroll
      for (int k = 1; k < 4; ++k) {
        const float v2 = s_qbv[row][l + k * 64];
        if (v2 > bv_) { bv_ = v2; bi_ = l + k * 64; }
      }
      #pragma unroll
      for (int m = 1; m < 64; m <<= 1) {
        const float ov = __shfl_xor(bv_, m);
        const int   oi = __shfl_xor(bi_, m);
        if (ov > bv_ || (ov == bv_ && oi < bi_)) { bv_ = ov; bi_ = oi; }
      }
      float uv_ = s_qu[row][l]; int ui_ = l;
      #pragma unroll
      for (int m = 1; m < 64; m <<= 1) {
        const float ov = __shfl_xor(uv_, m);
        const int   oi = __shfl_xor(ui_, m);
        if (ov > uv_ || (ov == uv_ && oi < ui_)) { uv_ = ov; ui_ = oi; }
      }
      if (l == 0) {
        const int n = r0 + row;
        const int fm = s_flag;
        float m;
        if (fm == 2)      m = (((const int*)wm)[n]   != 0)   ? 1.f : 0.f;
        else if (fm == 1) m = (((const float*)wm)[n] != 0.f) ? 1.f : 0.f;
        else              m = (wm[n] != 0)   ? 1.f : 0.f;
        const float wv = uv_ * bv_ * m;
        const int cell = ui_ * BD + bi_;
        denom[n]    = dsum;
        base_raw[n] = csum;
        wgt[n]      = wv;
        cellid[n]   = cell;
        mrow[n]     = m;
        if (m != 0.f) {
          atomicAdd(&sum_w[cell], wv);
          atomicAdd(&cnt[cell], 1.f);
        }
      }
    }
  }
}

// ---------------------------------------------------------------------------
// fp8 MFMA retrieve GEMM — 96-col tiles, SPLIT-K 2 (R20 winner) with
// DOUBLE-CHUNK PHASES: 64 phases x 48 MFMA, one vmcnt(6) wait + 6 ds_reads
// + 6 glls per phase (per-MFMA overhead halved vs R20). Same-phase slot
// reuse guarded by one lgkmcnt(0) between reads and prefetch (R11 pattern).
__global__ __launch_bounds__(256, 2) void mfma_gemm_kernel(
    const float* __restrict__ quT, const u8* __restrict__ qb8,
    const u8* __restrict__ PT8, float* __restrict__ out,
    int* __restrict__ tk, int* __restrict__ gf, int* __restrict__ claimed)
{
  __shared__ __attribute__((aligned(16))) u8 smB[4 * 4 * 3072];   // 48 KB
  __shared__ __attribute__((aligned(16))) float squT[32 * 128];   // 16 KB
  __shared__ int s_work;
  const int tid = threadIdx.x;
  const int wid = tid >> 6, lane = tid & 63;

  // tile-invariant lane geometry
  const int wr = (wid >> 1) * 64, wc = (wid & 1) * 48;
  const int fr = lane & 15, kg = lane >> 4;
  const int lrow  = lane >> 2;                         // staging row within 16
  const int sslot = (lane & 3) ^ ((lrow >> 1) & 3);    // source pre-swizzle
  u8* myB = smB + wid * 12288;
  int boff[3];
  #pragma unroll
  for (int nn = 0; nn < 3; ++nn)
    boff[nn] = (nn * 16 + fr) * 64 + ((kg ^ ((fr >> 1) & 3)) << 4);

  for (;;) {
    if (tid == 0) {
      unsigned int xcc;
      asm volatile("s_getreg_b32 %0, hwreg(HW_REG_XCC_ID)" : "=s"(xcc));
      const int x = (int)(xcc & 7u);
      const int t = atomicAdd(&tk[x], 1);
      int w = -1;
      if (t < 64) {
        const int cand = x * 64 + t;
        if (atomicCAS(&claimed[cand], 0, 1) == 0) w = cand;
      }
      while (w < 0) {
        const int g = atomicAdd(gf, 1);
        if (g >= 512) { w = -2; break; }
        if (atomicCAS(&claimed[g], 0, 1) == 0) w = g;
      }
      s_work = w;
    }
    __syncthreads();
    const int w = s_work;
    if (w < 0) return;

    const int bx = w & 31;
    const int combo = w >> 5;         // 0..15 (XCD x owns [2x, 2x+2))
    const int by = combo >> 1;        // 0..7 (== XCD on ticket path)
    const int bz = combo & 1;         // 0..1
    const int n0 = bx * 128;
    const int kbeg = bz * (UBD / 2);
    const int ubase = bz * 32;
    const int c0 = by * 96;

    // ---- A fragments: tile-constant registers
    longx2 afrag[4][4];
    {
      const u8* ga = qb8 + (size_t)(n0 + wr + fr) * BD + kg * 16;
      #pragma unroll
      for (int m = 0; m < 4; ++m)
        #pragma unroll
        for (int q = 0; q < 4; ++q)
          afrag[m][q] = *(const longx2*)(ga + (size_t)m * 16 * BD + q * 64);
    }

    // ---- prologue: squT 32 rows (4 glls/wave) + B chunks 0..3, one barrier
    #pragma unroll
    for (int i = 0; i < 4; ++i) {
      const int u = wid * 8 + i * 2 + (lane >> 5);
      const float* src = quT + (size_t)(ubase + u) * NR + n0 + (lane & 31) * 4;
      gll16(src, (u8*)squT + (wid * 8 + i * 2) * 512);
    }
    const u8* gB = PT8 + (size_t)(c0 + wc + lrow) * UBD + kbeg + sslot * 16;
    #pragma unroll
    for (int c = 0; c < 4; ++c)
      #pragma unroll
      for (int j = 0; j < 3; ++j)
        gll16(gB + (size_t)(j * 16) * UBD + c * 64, myB + c * 3072 + j * 1024);
    __syncthreads();   // all prologue DMAs drained (compiler vmcnt(0) at barrier)

    f32x4 accm[4][3], accu[4][3];
    #pragma unroll
    for (int m = 0; m < 4; ++m)
      #pragma unroll
      for (int nn = 0; nn < 3; ++nn)
        accm[m][nn] = (f32x4){0.f, 0.f, 0.f, 0.f};

    for (int ph2 = 0; ph2 < 64; ++ph2) {
      // wait: chunks 2ph2, 2ph2+1 landed; 2 newer chunks (6 glls) in flight
      if (ph2 < 63) asm volatile("s_waitcnt vmcnt(6)" ::: "memory");
      else          asm volatile("s_waitcnt vmcnt(0)" ::: "memory");
      const int pa = (2 * ph2) & 3;            // 0 or 2; second chunk = pa+1
      const u8* sba = myB + pa * 3072;
      const u8* sbb = myB + (pa + 1) * 3072;
      longx2 bva[3], bvb[3];
      #pragma unroll
      for (int nn = 0; nn < 3; ++nn) {
        bva[nn] = *(const longx2*)(sba + boff[nn]);
        bvb[nn] = *(const longx2*)(sbb + boff[nn]);
      }
      // WAR: this phase's prefetch re-targets slots pa, pa+1 (just read)
      asm volatile("s_waitcnt lgkmcnt(0)" ::: "memory");
      if (ph2 <= 61) {
        const u8* gsa = gB + (size_t)(2 * ph2 + 4) * 64;
        #pragma unroll
        for (int j = 0; j < 3; ++j) {
          gll16(gsa + (size_t)(j * 16) * UBD,      myB + pa * 3072 + j * 1024);
          gll16(gsa + (size_t)(j * 16) * UBD + 64, myB + (pa + 1) * 3072 + j * 1024);
        }
      }
      // ---- chunk A (k-quarter pa), then chunk B (pa+1): 48 MFMAs
      #pragma unroll
      for (int m = 0; m < 4; ++m)
        #pragma unroll
        for (int nn = 0; nn < 3; ++nn) {
          if (pa == 0)
            accu[m][nn] = __builtin_amdgcn_mfma_f32_16x16x32_fp8_fp8(
                afrag[m][0].x, bva[nn].x, (f32x4){0.f, 0.f, 0.f, 0.f}, 0, 0, 0);
          else
            accu[m][nn] = __builtin_amdgcn_mfma_f32_16x16x32_fp8_fp8(
                afrag[m][2].x, bva[nn].x, accu[m][nn], 0, 0, 0);
          accu[m][nn] = __builtin_amdgcn_mfma_f32_16x16x32_fp8_fp8(
              afrag[m][pa].y, bva[nn].y, accu[m][nn], 0, 0, 0);
          accu[m][nn] = __builtin_amdgcn_mfma_f32_16x16x32_fp8_fp8(
              afrag[m][pa + 1].x, bvb[nn].x, accu[m][nn], 0, 0, 0);
          accu[m][nn] = __builtin_amdgcn_mfma_f32_16x16x32_fp8_fp8(
              afrag[m][pa + 1].y, bvb[nn].y, accu[m][nn], 0, 0, 0);
        }
      if (pa == 2) {
        // completed u-chunk uc = ph2>>1
        const float* qs = squT + (ph2 >> 1) * 128 + wr + kg * 4;
        #pragma unroll
        for (int m = 0; m < 4; ++m) {
          const f32x4 qv = *(const f32x4*)(qs + m * 16);
          #pragma unroll
          for (int nn = 0; nn < 3; ++nn)
            accm[m][nn] += qv * accu[m][nn];
        }
      }
    }

    // ---- epilogue: atomic accumulate raw sums (scaled later by 1/denom)
    #pragma unroll
    for (int nn = 0; nn < 3; ++nn) {
      const int c = c0 + wc + nn * 16 + fr;
      float* obase; int ldO; int cc;
      if (c < 512) { obase = out + OFF_MDR;  ldO = RD; cc = c; }
      else         { obase = out + OFF_MSIG; ldO = SD; cc = c - 512; }
      #pragma unroll
      for (int m = 0; m < 4; ++m) {
        #pragma unroll
        for (int j = 0; j < 4; ++j) {
          const int r = n0 + wr + m * 16 + kg * 4 + j;
          atomicAdd(obase + (size_t)r * ldO + cc, accm[m][nn][j]);
        }
      }
    }
  }
}

// ---------------------------------------------------------------------------
// post_all: [0,4096) scale mdr/msig by 1/denom + conf | [4096,8192) ema_copy
// | [8192,8256) ema_small | [8256] stats (from usage+cnt)
__global__ __launch_bounds__(256) void post_all_kernel(
    const float* __restrict__ q_sigma, const float* __restrict__ denom,
    const float* __restrict__ base_raw,
    const float* __restrict__ dproto, const float* __restrict__ sproto,
    const float* __restrict__ ema, const float* __restrict__ usage,
    const float* __restrict__ sum_w, const float* __restrict__ cnt,
    float* __restrict__ out)
{
  __shared__ float r1[256], r2[256], r3[256];
  const int b = blockIdx.x;
  const int t = threadIdx.x;

  if (b < 4096) {
    const int n = b;
    const float d = denom[n];
    const float scale = (d > 0.f) ? (1.f / fmaxf(d, 1e-6f)) : 0.f;
    float* mdr = out + OFF_MDR + (size_t)n * RD;
    mdr[t]       *= scale;
    mdr[t + 256] *= scale;
    float* msig = out + OFF_MSIG + (size_t)n * SD;
    const float s = msig[t] * scale;
    msig[t] = s;
    const float a = q_sigma[(size_t)n * SD + t];
    const float bb = s + 1e-6f;
    r1[t] = a * a; r2[t] = bb * bb; r3[t] = a * bb;
    __syncthreads();
    for (int st = 128; st > 0; st >>= 1) {
      if (t < st) { r1[t] += r1[t + st]; r2[t] += r2[t + st]; r3[t] += r3[t + st]; }
      __syncthreads();
    }
    if (t == 0) {
      const float na = fmaxf(sqrtf(r1[0]), 1e-12f);
      const float nb = fmaxf(sqrtf(r2[0]), 1e-12f);
      const float cosv = r3[0] / (na * nb);
      const float agree = 0.5f * (1.f + cosv);
      const float base = (d > 0.f) ? base_raw[n] / fmaxf(d, 1e-6f) : 0.f;
      out[OFF_MCONF + n] = fminf(fmaxf(base * agree, 0.f), 1.f);
    }
    return;
  }
  if (b < 8192) {
    const size_t nd = (size_t)UBD * RD;
    const size_t total = nd + (size_t)UBD * SD;
    float* outd = out + OFF_NDP;
    float* outs = out + OFF_NSP;
    for (size_t i = (size_t)(b - 4096) * 256 + t; i < total;
         i += (size_t)4096 * 256) {
      if (i < nd) {
        const float p = dproto[i];
        outd[i] = (cnt[(int)(i >> 9)] > 0.f) ? DECAY * p : p;
      } else {
        const size_t j = i - nd;
        const float p = sproto[j];
        outs[j] = (cnt[(int)(j >> 8)] > 0.f) ? DECAY * p : p;
      }
    }
    return;
  }
  if (b < 8256) {
    const int i = (b - 8192) * 256 + t;
    const float c = cnt[i];
    const float cm = sum_w[i] / fmaxf(c, 1.f);
    out[OFF_NEC + i] = (c > 0.f) ? DECAY * ema[i] + (1.f - DECAY) * cm : ema[i];
    out[OFF_NUS + i] = usage[i] + c;
    return;
  }
  {
    float scnt = 0.f, snz = 0.f, sus = 0.f;
    for (int i = t; i < UBD; i += 256) {
      const float c = cnt[i]; scnt += c;
      const float u = usage[i] + c;
      if (u > 0.f) snz += 1.f;
      sus += u;
    }
    r1[t] = scnt; r2[t] = snz; r3[t] = sus;
    __syncthreads();
    for (int s = 128; s > 0; s >>= 1) {
      if (t < s) { r1[t] += r1[t + s]; r2[t] += r2[t + s]; r3[t] += r3[t + s]; }
      __syncthreads();
    }
    const float total_cnt = r1[0], total_nz = r2[0], total_us = r3[0];
    __syncthreads();
    const float S = fmaxf(total_us, 1e-6f);
    float ent = 0.f;
    for (int i = t; i < UBD; i += 256) {
      const float d = (usage[i] + cnt[i]) / S;
      ent += d * logf(d + 1e-6f);
    }
    r1[t] = ent;
    __syncthreads();
    for (int s = 128; s > 0; s >>= 1) {
      if (t < s) { r1[t] += r1[t + s]; }
      __syncthreads();
    }
    if (t == 0) {
      out[OFF_SCAL + 0] = total_cnt / (float)NR;
      out[OFF_SCAL + 1] = total_nz / (float)UBD;
      out[OFF_SCAL + 2] = -r1[0] / 9.70406053f;   // ln(16384)
    }
  }
}

// ---------------------------------------------------------------------------
// Add (1-DECAY) * (w/cs) * target onto the DECAY-scaled protos
__global__ __launch_bounds__(256) void scatter2_kernel(
    const float* __restrict__ dtarget, const float* __restrict__ q_sigma,
    const float* __restrict__ wgt, const int* __restrict__ cellid,
    const float* __restrict__ mrow, const float* __restrict__ sum_w,
    float* __restrict__ outd, float* __restrict__ outs)
{
  const int n = blockIdx.x;
  if (mrow[n] == 0.f) return;
  const int t = threadIdx.x;
  const int c = cellid[n];
  const float cs = fmaxf(sum_w[c], 1e-6f);
  const float coef = (1.0f - DECAY) * wgt[n] / cs;
  atomicAdd(&outd[(size_t)c * RD + t],       dtarget[(size_t)n * RD + t] * coef);
  atomicAdd(&outd[(size_t)c * RD + t + 256], dtarget[(size_t)n * RD + t + 256] * coef);
  atomicAdd(&outs[(size_t)c * SD + t],       q_sigma[(size_t)n * SD + t] * coef);
}

// ---------------------------------------------------------------------------
extern "C" void kernel_launch(void* const* d_in, const int* in_sizes, int n_in,
                              void* d_out, int out_size, void* d_ws, size_t ws_size,
                              hipStream_t stream)
{
  const float* q_u    = (const float*)d_in[0];
  const float* q_b    = (const float*)d_in[1];
  const float* q_sig  = (const float*)d_in[2];
  const float* dtg    = (const float*)d_in[3];
  const unsigned char* wm = (const unsigned char*)d_in[4];
  const float* dproto = (const float*)d_in[5];
  const float* sproto = (const float*)d_in[6];
  const float* ema    = (const float*)d_in[7];
  const float* usage  = (const float*)d_in[8];
  float* out = (float*)d_out;

  float* wsf = (float*)d_ws;
  int*   wsi = (int*)d_ws;
  float* denom    = wsf + 16;                  // [4096]
  float* base_raw = wsf + 16 + 4096;           // [4096]
  float* wgtb     = wsf + 16 + 8192;           // [4096]
  int*   cellid   = wsi + 16 + 12288;          // [4096]
  float* mrow     = wsf + 16 + 16384;          // [4096]
  float* sum_w    = wsf + 20496;               // [16384]
  float* cnt      = wsf + 20496 + 16384;       // [16384]
  int*   tk       = wsi + 53264;               // [8]
  int*   gf       = wsi + 53272;               // [1] (+7 pad)
  int*   claimed  = wsi + 53280;               // [512]

  // PT8 (12.6 MB) + qb8 (1 MB) + quT (1 MB) park in the NDP output region,
  // rewritten (post_all/scatter2) only after the GEMM consumed them.
  u8*    PT8 = (u8*)(out + OFF_NDP);
  u8*    qb8 = PT8 + (size_t)768 * UBD;
  float* quT = (float*)(qb8 + (size_t)NR * BD);

  // zero raw-sum targets (MDR+MSIG, atomic epilogue) and ws accumulators
  hipMemsetAsync(out, 0, (size_t)OFF_MCONF * sizeof(float), stream);
  hipMemsetAsync(sum_w, 0, (2u * UBD + 16 + 512) * sizeof(float), stream);

  prep_all_kernel<<<4416, 256, 0, stream>>>(q_u, q_b, dproto, sproto,
                                            usage, ema, wm, qb8, quT, PT8,
                                            denom, base_raw, wgtb, cellid, mrow,
                                            sum_w, cnt);
  mfma_gemm_kernel<<<512, 256, 0, stream>>>(quT, qb8, PT8, out, tk, gf, claimed);
  post_all_kernel<<<8257, 256, 0, stream>>>(q_sig, denom, base_raw, dproto,
                                            sproto, ema, usage, sum_w, cnt, out);
  scatter2_kernel<<<NR, 256, 0, stream>>>(dtg, q_sig, wgtb, cellid, mrow, sum_w,
                                          out + OFF_NDP, out + OFF_NSP);
}

// Round 22
// 184.699 us; speedup vs baseline: 1.5344x; 1.5344x over previous
//
#include <hip/hip_runtime.h>
#include <hip/hip_fp8.h>
#include <math.h>

#define NR 4096
#define UD 64
#define BD 256
#define SD 256
#define RD 512
#define UBD 16384
#define DECAY 0.99f

typedef unsigned char u8;
typedef __attribute__((ext_vector_type(4))) float f32x4;
typedef __attribute__((ext_vector_type(2))) long longx2;

// output offsets (in floats), concatenated in reference return order
#define OFF_MDR   0ull
#define OFF_MSIG  2097152ull
#define OFF_MCONF 3145728ull
#define OFF_NDP   3149824ull
#define OFF_NSP   11538432ull
#define OFF_NEC   15732736ull
#define OFF_NUS   15749120ull
#define OFF_SCAL  15765504ull

static __device__ __forceinline__ u8 f2e4m3(float x) {
  __hip_fp8_e4m3 h(x);
  return (u8)h.__x;
}

static __device__ __forceinline__ void gll16(const void* g, void* l) {
  __builtin_amdgcn_global_load_lds(
      (const __attribute__((address_space(1))) unsigned int*)g,
      (__attribute__((address_space(3))) unsigned int*)l, 16, 0, 0);
}

// k-order permutation within a 64-block: b = ks8*32 + kg*8 + e -> kg*16 + ks8*8 + e
static __device__ __forceinline__ int perm64(int x) {
  return (((x >> 3) & 3) << 4) | (((x >> 5) & 1) << 3) | (x & 7);
}

// ---------------------------------------------------------------------------
// prep_all: [0,1024) qb8 convert | [1024,1088) quT | [1088,4160) PT8 transpose
// | [4160,4416) row_prep (16 rows/block, fused sum_w/cnt atomics)
__global__ __launch_bounds__(256) void prep_all_kernel(
    const float* __restrict__ q_u, const float* __restrict__ q_b,
    const float* __restrict__ dproto, const float* __restrict__ sproto,
    const float* __restrict__ usage, const float* __restrict__ ema,
    const unsigned char* __restrict__ wm,
    u8* __restrict__ qb8, float* __restrict__ quT, u8* __restrict__ PT8,
    float* __restrict__ denom, float* __restrict__ base_raw,
    float* __restrict__ wgt, int* __restrict__ cellid, float* __restrict__ mrow,
    float* __restrict__ sum_w, float* __restrict__ cnt)
{
  __shared__ __attribute__((aligned(16))) u8 sbuf[53248];
  __shared__ int s_flag;
  const int b = blockIdx.x;
  const int tid = threadIdx.x;

  if (b < 1024) {
    const int i = b * 256 + tid;
    const int idx = i * 4;
    const int row = idx >> 8;
    const int bb  = idx & 255;
    const float4 v = *(const float4*)(q_b + (size_t)idx);
    u8 tmp[4] = { f2e4m3(v.x), f2e4m3(v.y), f2e4m3(v.z), f2e4m3(v.w) };
    unsigned int wv; __builtin_memcpy(&wv, tmp, 4);
    const int nb = (bb & ~63) | perm64(bb & 63);
    *(unsigned int*)(qb8 + (size_t)row * BD + nb) = wv;
    return;
  }
  if (b < 1088) {
    float (*s)[65] = (float(*)[65])sbuf;
    const int n0 = (b - 1024) * 64;
    #pragma unroll
    for (int i = 0; i < 16; ++i) {
      const int idx = tid + i * 256;
      const int r = idx >> 6, u = idx & 63;
      s[r][u] = q_u[(size_t)(n0 + r) * UD + u];
    }
    __syncthreads();
    #pragma unroll
    for (int i = 0; i < 16; ++i) {
      const int idx = tid + i * 256;
      const int u = idx >> 6, r = idx & 63;
      quT[(size_t)u * NR + n0 + r] = s[r][u];
    }
    return;
  }
  if (b < 4160) {
    u8 (*s)[68] = (u8(*)[68])sbuf;
    const int idx = b - 1088;
    const int k0 = (idx & 255) * 64;
    const int rblk = idx >> 8;       // 0..11
    const float* src; int ld; int c0s;
    if (rblk < 8) { src = dproto; ld = RD; c0s = rblk * 64; }
    else          { src = sproto; ld = SD; c0s = (rblk - 8) * 64; }
    const int kl = tid >> 4;
    const int rl = (tid & 15) * 4;
    #pragma unroll
    for (int i = 0; i < 4; ++i) {
      const int k = kl + i * 16;
      const bool valid = usage[k0 + k] > 0.f;
      const float4 v = *(const float4*)(src + (size_t)(k0 + k) * ld + c0s + rl);
      s[k][rl + 0] = valid ? f2e4m3(v.x) : (u8)0;
      s[k][rl + 1] = valid ? f2e4m3(v.y) : (u8)0;
      s[k][rl + 2] = valid ? f2e4m3(v.z) : (u8)0;
      s[k][rl + 3] = valid ? f2e4m3(v.w) : (u8)0;
    }
    __syncthreads();
    const int rl2 = tid >> 4;
    const int kl2 = (tid & 15) * 4;
    #pragma unroll
    for (int i = 0; i < 4; ++i) {
      const int r = rl2 + i * 16;
      u8 tmp[4] = { s[kl2 + 0][r], s[kl2 + 1][r], s[kl2 + 2][r], s[kl2 + 3][r] };
      unsigned int wv; __builtin_memcpy(&wv, tmp, 4);
      *(unsigned int*)(PT8 + (size_t)(rblk * 64 + r) * UBD + k0 + perm64(kl2)) = wv;
    }
    return;
  }
  // ---- row_prep: 16 rows/block
  {
    float (*s_qu)[64]   = (float(*)[64])sbuf;
    float (*s_qbv)[256] = (float(*)[256])(sbuf + 4096);
    float (*s_pd)[256]  = (float(*)[256])(sbuf + 20480);
    float (*s_pc)[256]  = (float(*)[256])(sbuf + 36864);
    const int r0 = (b - 4160) * 16;
    {
      const float4 v = *(const float4*)(q_u + (size_t)r0 * UD + tid * 4);
      float* dst = &s_qu[0][0] + tid * 4;
      dst[0] = v.x; dst[1] = v.y; dst[2] = v.z; dst[3] = v.w;
    }
    {
      const float4* src = (const float4*)(q_b + (size_t)r0 * BD);
      float4* dst = (float4*)&s_qbv[0][0];
      #pragma unroll
      for (int i = 0; i < 4; ++i) dst[tid + i * 256] = src[tid + i * 256];
    }
    if (tid == 0) {
      const int*   wi = (const int*)wm;
      const float* wf = (const float*)wm;
      bool is_i32 = true, is_f32 = true;
      #pragma unroll
      for (int i = 0; i < 16; ++i) {
        int v = wi[i];
        if (v != 0 && v != 1) is_i32 = false;
        float f = wf[i];
        if (f != 0.f && f != 1.f) is_f32 = false;
      }
      s_flag = is_i32 ? 2 : (is_f32 ? 1 : 0);
    }
    __syncthreads();
    float accd[16], accc[16];
    #pragma unroll
    for (int r = 0; r < 16; ++r) { accd[r] = 0.f; accc[r] = 0.f; }
    #pragma unroll 2
    for (int u = 0; u < UD; ++u) {
      const float us = usage[u * BD + tid];
      const float em = ema[u * BD + tid];
      const float vm = (us > 0.f) ? 1.f : 0.f;
      const float ev = em * vm;
      #pragma unroll
      for (int r = 0; r < 16; ++r) {
        accd[r] += s_qu[r][u] * vm;
        accc[r] += s_qu[r][u] * ev;
      }
    }
    #pragma unroll
    for (int r = 0; r < 16; ++r) {
      s_pd[r][tid] = accd[r] * s_qbv[r][tid];
      s_pc[r][tid] = accc[r] * s_qbv[r][tid];
    }
    __syncthreads();
    const int w = tid >> 6, l = tid & 63;
    #pragma unroll
    for (int rr = 0; rr < 4; ++rr) {
      const int row = w * 4 + rr;
      float dsum = s_pd[row][l] + s_pd[row][l + 64] + s_pd[row][l + 128] + s_pd[row][l + 192];
      float csum = s_pc[row][l] + s_pc[row][l + 64] + s_pc[row][l + 128] + s_pc[row][l + 192];
      #pragma unroll
      for (int m = 1; m < 64; m <<= 1) {
        dsum += __shfl_xor(dsum, m);
        csum += __shfl_xor(csum, m);
      }
      float bv_ = s_qbv[row][l]; int bi_ = l;
      #pragma unroll
      for (int k = 1; k < 4; ++k) {
        const float v2 = s_qbv[row][l + k * 64];
        if (v2 > bv_) { bv_ = v2; bi_ = l + k * 64; }
      }
      #pragma unroll
      for (int m = 1; m < 64; m <<= 1) {
        const float ov = __shfl_xor(bv_, m);
        const int   oi = __shfl_xor(bi_, m);
        if (ov > bv_ || (ov == bv_ && oi < bi_)) { bv_ = ov; bi_ = oi; }
      }
      float uv_ = s_qu[row][l]; int ui_ = l;
      #pragma unroll
      for (int m = 1; m < 64; m <<= 1) {
        const float ov = __shfl_xor(uv_, m);
        const int   oi = __shfl_xor(ui_, m);
        if (ov > uv_ || (ov == uv_ && oi < ui_)) { uv_ = ov; ui_ = oi; }
      }
      if (l == 0) {
        const int n = r0 + row;
        const int fm = s_flag;
        float m;
        if (fm == 2)      m = (((const int*)wm)[n]   != 0)   ? 1.f : 0.f;
        else if (fm == 1) m = (((const float*)wm)[n] != 0.f) ? 1.f : 0.f;
        else              m = (wm[n] != 0)   ? 1.f : 0.f;
        const float wv = uv_ * bv_ * m;
        const int cell = ui_ * BD + bi_;
        denom[n]    = dsum;
        base_raw[n] = csum;
        wgt[n]      = wv;
        cellid[n]   = cell;
        mrow[n]     = m;
        if (m != 0.f) {
          atomicAdd(&sum_w[cell], wv);
          atomicAdd(&cnt[cell], 1.f);
        }
      }
    }
  }
}

// ---------------------------------------------------------------------------
// fp8 MFMA retrieve GEMM — 96-col tiles, SPLIT-K 2: 512 tiles (32 bx x 8 by
// x 2 bz) on 512 persistent blocks = exactly 1 tile/block. Per-wave private
// 4-slot ring, depth-3 prefetch (single-chunk cadence — load-bearing for L2
// residency, R21's double-chunk phase thrashed L2), counted vmcnt(6), no WAR
// fence. Best measured config (R20: 86.3us, MfmaUtil 47.6%).
__global__ __launch_bounds__(256, 2) void mfma_gemm_kernel(
    const float* __restrict__ quT, const u8* __restrict__ qb8,
    const u8* __restrict__ PT8, float* __restrict__ out,
    int* __restrict__ tk, int* __restrict__ gf, int* __restrict__ claimed)
{
  __shared__ __attribute__((aligned(16))) u8 smB[4 * 4 * 3072];   // 48 KB
  __shared__ __attribute__((aligned(16))) float squT[32 * 128];   // 16 KB
  __shared__ int s_work;
  const int tid = threadIdx.x;
  const int wid = tid >> 6, lane = tid & 63;

  // tile-invariant lane geometry
  const int wr = (wid >> 1) * 64, wc = (wid & 1) * 48;
  const int fr = lane & 15, kg = lane >> 4;
  const int lrow  = lane >> 2;                         // staging row within 16
  const int sslot = (lane & 3) ^ ((lrow >> 1) & 3);    // source pre-swizzle
  u8* myB = smB + wid * 12288;
  int boff[3];
  #pragma unroll
  for (int nn = 0; nn < 3; ++nn)
    boff[nn] = (nn * 16 + fr) * 64 + ((kg ^ ((fr >> 1) & 3)) << 4);

  for (;;) {
    if (tid == 0) {
      unsigned int xcc;
      asm volatile("s_getreg_b32 %0, hwreg(HW_REG_XCC_ID)" : "=s"(xcc));
      const int x = (int)(xcc & 7u);
      const int t = atomicAdd(&tk[x], 1);
      int w = -1;
      if (t < 64) {
        const int cand = x * 64 + t;
        if (atomicCAS(&claimed[cand], 0, 1) == 0) w = cand;
      }
      while (w < 0) {
        const int g = atomicAdd(gf, 1);
        if (g >= 512) { w = -2; break; }
        if (atomicCAS(&claimed[g], 0, 1) == 0) w = g;
      }
      s_work = w;
    }
    __syncthreads();
    const int w = s_work;
    if (w < 0) return;

    const int bx = w & 31;
    const int combo = w >> 5;         // 0..15 (XCD x owns [2x, 2x+2))
    const int by = combo >> 1;        // 0..7 (== XCD on ticket path)
    const int bz = combo & 1;         // 0..1
    const int n0 = bx * 128;
    const int kbeg = bz * (UBD / 2);
    const int ubase = bz * 32;
    const int c0 = by * 96;

    // ---- A fragments: tile-constant registers
    longx2 afrag[4][4];
    {
      const u8* ga = qb8 + (size_t)(n0 + wr + fr) * BD + kg * 16;
      #pragma unroll
      for (int m = 0; m < 4; ++m)
        #pragma unroll
        for (int q = 0; q < 4; ++q)
          afrag[m][q] = *(const longx2*)(ga + (size_t)m * 16 * BD + q * 64);
    }

    // ---- prologue: squT 32 rows (4 glls/wave) + B chunks 0..2, one barrier
    #pragma unroll
    for (int i = 0; i < 4; ++i) {
      const int u = wid * 8 + i * 2 + (lane >> 5);
      const float* src = quT + (size_t)(ubase + u) * NR + n0 + (lane & 31) * 4;
      gll16(src, (u8*)squT + (wid * 8 + i * 2) * 512);
    }
    const u8* gB = PT8 + (size_t)(c0 + wc + lrow) * UBD + kbeg + sslot * 16;
    #pragma unroll
    for (int c = 0; c < 3; ++c)
      #pragma unroll
      for (int j = 0; j < 3; ++j)
        gll16(gB + (size_t)(j * 16) * UBD + c * 64, myB + c * 3072 + j * 1024);
    __syncthreads();   // all prologue DMAs drained (compiler vmcnt(0) at barrier)

    f32x4 accm[4][3], accu[4][3];
    #pragma unroll
    for (int m = 0; m < 4; ++m)
      #pragma unroll
      for (int nn = 0; nn < 3; ++nn)
        accm[m][nn] = (f32x4){0.f, 0.f, 0.f, 0.f};

    for (int uc = 0; uc < 32; ++uc) {
      #pragma unroll
      for (int p4 = 0; p4 < 4; ++p4) {
        const int ph = uc * 4 + p4;
        // counted wait: chunk ph landed; up to 2 newer chunks in flight
        if (ph < 126)       asm volatile("s_waitcnt vmcnt(6)" ::: "memory");
        else if (ph == 126) asm volatile("s_waitcnt vmcnt(3)" ::: "memory");
        else                asm volatile("s_waitcnt vmcnt(0)" ::: "memory");
        const u8* sb = myB + (ph & 3) * 3072;
        longx2 bv[3];
        #pragma unroll
        for (int nn = 0; nn < 3; ++nn)
          bv[nn] = *(const longx2*)(sb + boff[nn]);
        // prefetch chunk ph+3 into slot (ph+3)&3 == (ph-1)&3 (reads finished)
        if (ph < 125) {
          const u8* gs = gB + (size_t)(ph + 3) * 64;
          u8* ld = myB + ((ph + 3) & 3) * 3072;
          #pragma unroll
          for (int j = 0; j < 3; ++j)
            gll16(gs + (size_t)(j * 16) * UBD, ld + j * 1024);
        }
        #pragma unroll
        for (int m = 0; m < 4; ++m)
          #pragma unroll
          for (int nn = 0; nn < 3; ++nn) {
            if (p4 == 0)
              accu[m][nn] = __builtin_amdgcn_mfma_f32_16x16x32_fp8_fp8(
                  afrag[m][p4].x, bv[nn].x, (f32x4){0.f, 0.f, 0.f, 0.f}, 0, 0, 0);
            else
              accu[m][nn] = __builtin_amdgcn_mfma_f32_16x16x32_fp8_fp8(
                  afrag[m][p4].x, bv[nn].x, accu[m][nn], 0, 0, 0);
            accu[m][nn] = __builtin_amdgcn_mfma_f32_16x16x32_fp8_fp8(
                afrag[m][p4].y, bv[nn].y, accu[m][nn], 0, 0, 0);
          }
        if (p4 == 3) {
          const float* qs = squT + uc * 128 + wr + kg * 4;
          #pragma unroll
          for (int m = 0; m < 4; ++m) {
            const f32x4 qv = *(const f32x4*)(qs + m * 16);
            #pragma unroll
            for (int nn = 0; nn < 3; ++nn)
              accm[m][nn] += qv * accu[m][nn];
          }
        }
      }
    }

    // ---- epilogue: atomic accumulate raw sums (scaled later by 1/denom)
    #pragma unroll
    for (int nn = 0; nn < 3; ++nn) {
      const int c = c0 + wc + nn * 16 + fr;
      float* obase; int ldO; int cc;
      if (c < 512) { obase = out + OFF_MDR;  ldO = RD; cc = c; }
      else         { obase = out + OFF_MSIG; ldO = SD; cc = c - 512; }
      #pragma unroll
      for (int m = 0; m < 4; ++m) {
        #pragma unroll
        for (int j = 0; j < 4; ++j) {
          const int r = n0 + wr + m * 16 + kg * 4 + j;
          atomicAdd(obase + (size_t)r * ldO + cc, accm[m][nn][j]);
        }
      }
    }
  }
}

// ---------------------------------------------------------------------------
// post_all: [0,4096) scale mdr/msig by 1/denom + conf | [4096,8192) ema_copy
// | [8192,8256) ema_small | [8256] stats (from usage+cnt)
__global__ __launch_bounds__(256) void post_all_kernel(
    const float* __restrict__ q_sigma, const float* __restrict__ denom,
    const float* __restrict__ base_raw,
    const float* __restrict__ dproto, const float* __restrict__ sproto,
    const float* __restrict__ ema, const float* __restrict__ usage,
    const float* __restrict__ sum_w, const float* __restrict__ cnt,
    float* __restrict__ out)
{
  __shared__ float r1[256], r2[256], r3[256];
  const int b = blockIdx.x;
  const int t = threadIdx.x;

  if (b < 4096) {
    const int n = b;
    const float d = denom[n];
    const float scale = (d > 0.f) ? (1.f / fmaxf(d, 1e-6f)) : 0.f;
    float* mdr = out + OFF_MDR + (size_t)n * RD;
    mdr[t]       *= scale;
    mdr[t + 256] *= scale;
    float* msig = out + OFF_MSIG + (size_t)n * SD;
    const float s = msig[t] * scale;
    msig[t] = s;
    const float a = q_sigma[(size_t)n * SD + t];
    const float bb = s + 1e-6f;
    r1[t] = a * a; r2[t] = bb * bb; r3[t] = a * bb;
    __syncthreads();
    for (int st = 128; st > 0; st >>= 1) {
      if (t < st) { r1[t] += r1[t + st]; r2[t] += r2[t + st]; r3[t] += r3[t + st]; }
      __syncthreads();
    }
    if (t == 0) {
      const float na = fmaxf(sqrtf(r1[0]), 1e-12f);
      const float nb = fmaxf(sqrtf(r2[0]), 1e-12f);
      const float cosv = r3[0] / (na * nb);
      const float agree = 0.5f * (1.f + cosv);
      const float base = (d > 0.f) ? base_raw[n] / fmaxf(d, 1e-6f) : 0.f;
      out[OFF_MCONF + n] = fminf(fmaxf(base * agree, 0.f), 1.f);
    }
    return;
  }
  if (b < 8192) {
    const size_t nd = (size_t)UBD * RD;
    const size_t total = nd + (size_t)UBD * SD;
    float* outd = out + OFF_NDP;
    float* outs = out + OFF_NSP;
    for (size_t i = (size_t)(b - 4096) * 256 + t; i < total;
         i += (size_t)4096 * 256) {
      if (i < nd) {
        const float p = dproto[i];
        outd[i] = (cnt[(int)(i >> 9)] > 0.f) ? DECAY * p : p;
      } else {
        const size_t j = i - nd;
        const float p = sproto[j];
        outs[j] = (cnt[(int)(j >> 8)] > 0.f) ? DECAY * p : p;
      }
    }
    return;
  }
  if (b < 8256) {
    const int i = (b - 8192) * 256 + t;
    const float c = cnt[i];
    const float cm = sum_w[i] / fmaxf(c, 1.f);
    out[OFF_NEC + i] = (c > 0.f) ? DECAY * ema[i] + (1.f - DECAY) * cm : ema[i];
    out[OFF_NUS + i] = usage[i] + c;
    return;
  }
  {
    float scnt = 0.f, snz = 0.f, sus = 0.f;
    for (int i = t; i < UBD; i += 256) {
      const float c = cnt[i]; scnt += c;
      const float u = usage[i] + c;
      if (u > 0.f) snz += 1.f;
      sus += u;
    }
    r1[t] = scnt; r2[t] = snz; r3[t] = sus;
    __syncthreads();
    for (int s = 128; s > 0; s >>= 1) {
      if (t < s) { r1[t] += r1[t + s]; r2[t] += r2[t + s]; r3[t] += r3[t + s]; }
      __syncthreads();
    }
    const float total_cnt = r1[0], total_nz = r2[0], total_us = r3[0];
    __syncthreads();
    const float S = fmaxf(total_us, 1e-6f);
    float ent = 0.f;
    for (int i = t; i < UBD; i += 256) {
      const float d = (usage[i] + cnt[i]) / S;
      ent += d * logf(d + 1e-6f);
    }
    r1[t] = ent;
    __syncthreads();
    for (int s = 128; s > 0; s >>= 1) {
      if (t < s) { r1[t] += r1[t + s]; }
      __syncthreads();
    }
    if (t == 0) {
      out[OFF_SCAL + 0] = total_cnt / (float)NR;
      out[OFF_SCAL + 1] = total_nz / (float)UBD;
      out[OFF_SCAL + 2] = -r1[0] / 9.70406053f;   // ln(16384)
    }
  }
}

// ---------------------------------------------------------------------------
// Add (1-DECAY) * (w/cs) * target onto the DECAY-scaled protos
__global__ __launch_bounds__(256) void scatter2_kernel(
    const float* __restrict__ dtarget, const float* __restrict__ q_sigma,
    const float* __restrict__ wgt, const int* __restrict__ cellid,
    const float* __restrict__ mrow, const float* __restrict__ sum_w,
    float* __restrict__ outd, float* __restrict__ outs)
{
  const int n = blockIdx.x;
  if (mrow[n] == 0.f) return;
  const int t = threadIdx.x;
  const int c = cellid[n];
  const float cs = fmaxf(sum_w[c], 1e-6f);
  const float coef = (1.0f - DECAY) * wgt[n] / cs;
  atomicAdd(&outd[(size_t)c * RD + t],       dtarget[(size_t)n * RD + t] * coef);
  atomicAdd(&outd[(size_t)c * RD + t + 256], dtarget[(size_t)n * RD + t + 256] * coef);
  atomicAdd(&outs[(size_t)c * SD + t],       q_sigma[(size_t)n * SD + t] * coef);
}

// ---------------------------------------------------------------------------
extern "C" void kernel_launch(void* const* d_in, const int* in_sizes, int n_in,
                              void* d_out, int out_size, void* d_ws, size_t ws_size,
                              hipStream_t stream)
{
  const float* q_u    = (const float*)d_in[0];
  const float* q_b    = (const float*)d_in[1];
  const float* q_sig  = (const float*)d_in[2];
  const float* dtg    = (const float*)d_in[3];
  const unsigned char* wm = (const unsigned char*)d_in[4];
  const float* dproto = (const float*)d_in[5];
  const float* sproto = (const float*)d_in[6];
  const float* ema    = (const float*)d_in[7];
  const float* usage  = (const float*)d_in[8];
  float* out = (float*)d_out;

  float* wsf = (float*)d_ws;
  int*   wsi = (int*)d_ws;
  float* denom    = wsf + 16;                  // [4096]
  float* base_raw = wsf + 16 + 4096;           // [4096]
  float* wgtb     = wsf + 16 + 8192;           // [4096]
  int*   cellid   = wsi + 16 + 12288;          // [4096]
  float* mrow     = wsf + 16 + 16384;          // [4096]
  float* sum_w    = wsf + 20496;               // [16384]
  float* cnt      = wsf + 20496 + 16384;       // [16384]
  int*   tk       = wsi + 53264;               // [8]
  int*   gf       = wsi + 53272;               // [1] (+7 pad)
  int*   claimed  = wsi + 53280;               // [512]

  // PT8 (12.6 MB) + qb8 (1 MB) + quT (1 MB) park in the NDP output region,
  // rewritten (post_all/scatter2) only after the GEMM consumed them.
  u8*    PT8 = (u8*)(out + OFF_NDP);
  u8*    qb8 = PT8 + (size_t)768 * UBD;
  float* quT = (float*)(qb8 + (size_t)NR * BD);

  // zero raw-sum targets (MDR+MSIG, atomic epilogue) and ws accumulators
  hipMemsetAsync(out, 0, (size_t)OFF_MCONF * sizeof(float), stream);
  hipMemsetAsync(sum_w, 0, (2u * UBD + 16 + 512) * sizeof(float), stream);

  prep_all_kernel<<<4416, 256, 0, stream>>>(q_u, q_b, dproto, sproto,
                                            usage, ema, wm, qb8, quT, PT8,
                                            denom, base_raw, wgtb, cellid, mrow,
                                            sum_w, cnt);
  mfma_gemm_kernel<<<512, 256, 0, stream>>>(quT, qb8, PT8, out, tk, gf, claimed);
  post_all_kernel<<<8257, 256, 0, stream>>>(q_sig, denom, base_raw, dproto,
                                            sproto, ema, usage, sum_w, cnt, out);
  scatter2_kernel<<<NR, 256, 0, stream>>>(dtg, q_sig, wgtb, cellid, mrow, sum_w,
                                          out + OFF_NDP, out + OFF_NSP);
}